// Round 5
// baseline (1685.962 us; speedup 1.0000x reference)
//
#include <hip/hip_runtime.h>
#include <stdint.h>

typedef unsigned short u16;
typedef unsigned int   u32;
typedef short  s8v  __attribute__((ext_vector_type(8)));
typedef __bf16 bf8v __attribute__((ext_vector_type(8)));
typedef float  f4v  __attribute__((ext_vector_type(4)));
typedef u16    u16x8 __attribute__((ext_vector_type(8)));

#define NTOK   16384
#define HD     512
#define FD     2048
#define NE     8
#define MAXROWS 33280
#define MAXTILES 520

// ws layout (bytes); total need = 51380224
// Inputs are float32 (proven R3/R4: bf16-read gave NaN, f32-read finite); output is float32
// (reference returns f32; stub contract: non-bf16 reference output -> float*).
#define CTRL_OFF   0          // ints: [0..7] counts, [8..15] fill, [16..23] segoff, [24] rows, [25] tiles, [32..] map
#define TOKE_OFF   8192       // int[NTOK]
#define COMB_OFF   73728      // float[NTOK*8]
#define LIST_OFF   598016     // int[MAXROWS]
#define ROWW_OFF   731136     // float[MAXROWS]
#define XBF_OFF    1048576    // u16 [NTOK][HD]        bf16 copy of x
#define W1T_OFF    17825792   // u16 [NE][FD][HD]      bf16, transposed
#define W2T_OFF    34603008   // u16 [NE][HD][FD]      bf16, transposed
#define WS_NEED    51380224ull

__device__ __forceinline__ u16 f2bf(float f) {
    union { float f; u32 u; } v; v.f = f;
    u32 r = v.u + 0x7FFFu + ((v.u >> 16) & 1u);
    return (u16)(r >> 16);
}
__device__ __forceinline__ float gelu_f(float v) {
    float u = 0.7978845608028654f * (v + 0.044715f * v * v * v);
    float t = 1.f - 2.f / (__expf(2.f * u) + 1.f);
    return 0.5f * v * (1.f + t);
}

// mfma wrapper: ROCm versions differ on whether the builtin takes v8i16 or v8bf16.
template <typename V>
__device__ __forceinline__ auto mfma_try(V a, V b, f4v c, int)
    -> decltype(__builtin_amdgcn_mfma_f32_16x16x32_bf16(a, b, c, 0, 0, 0)) {
    return __builtin_amdgcn_mfma_f32_16x16x32_bf16(a, b, c, 0, 0, 0);
}
template <typename V>
__device__ __forceinline__ f4v mfma_try(V a, V b, f4v c, long) {
    return __builtin_amdgcn_mfma_f32_16x16x32_bf16(
        __builtin_bit_cast(bf8v, a), __builtin_bit_cast(bf8v, b), c, 0, 0, 0);
}
__device__ __forceinline__ f4v mfma16(s8v a, s8v b, f4v c) { return mfma_try(a, b, c, 0); }

// ---------------- diagnostic fallback: ws too small -> clean absmax 2.484 failure ----------------
__global__ __launch_bounds__(256) void k_fallback(float* __restrict__ out) {
    int i = (blockIdx.x * 256 + threadIdx.x) * 4;
    *(f4v*)(out + i) = (f4v){0.f, 0.f, 0.f, 0.f};
}

// ---------------- zero per-call state (harness re-poisons d_out/ws to 0xAA every launch) ----------------
__global__ __launch_bounds__(256) void k_zero(int* __restrict__ ctrl, int* __restrict__ list,
                                              float* __restrict__ roww, float* __restrict__ out) {
    int id = blockIdx.x * 256 + threadIdx.x;
    *(f4v*)(out + (size_t)id * 4) = (f4v){0.f, 0.f, 0.f, 0.f};
    if (id < MAXROWS) { list[id] = 0; roww[id] = 0.f; }
    if (id < 64) ctrl[id] = 0;
}

// ---------------- transpose+cast: f32 in [R][C] -> bf16 out [C][R], per expert ----------------
__global__ __launch_bounds__(256) void k_transpose(const float* __restrict__ in, u16* __restrict__ out,
                                                   int R, int C) {
    __shared__ float tile[64][65];
    size_t base = (size_t)blockIdx.z * R * C;
    const float* ip = in + base;
    u16* op = out + base;
    int c0 = blockIdx.x * 64, r0 = blockIdx.y * 64;
#pragma unroll
    for (int i = 0; i < 16; i++) {
        int idx = threadIdx.x + i * 256;
        int r = idx >> 6, c = idx & 63;
        tile[r][c] = ip[(size_t)(r0 + r) * C + c0 + c];
    }
    __syncthreads();
#pragma unroll
    for (int i = 0; i < 16; i++) {
        int idx = threadIdx.x + i * 256;
        int rr = idx >> 6, cc = idx & 63;
        op[(size_t)(c0 + rr) * R + r0 + cc] = f2bf(tile[cc][rr]);
    }
}

// ---------------- gating (f32): softmax + top2, one wave per token; also writes bf16 x copy ----------------
__global__ __launch_bounds__(256) void k_gate(const float* __restrict__ x, const float* __restrict__ Wg,
                                              const float* __restrict__ bg, float* __restrict__ comb,
                                              int* __restrict__ toke, int* __restrict__ ctrl,
                                              u16* __restrict__ xbf) {
    int lane = threadIdx.x & 63;
    int t = (blockIdx.x * 4 + (threadIdx.x >> 6)) & (NTOK - 1);
    const float* xr = x + (size_t)t * HD;
    f4v xa = *(const f4v*)(xr + lane * 8);
    f4v xb = *(const f4v*)(xr + lane * 8 + 4);
    u16x8 o;
#pragma unroll
    for (int j = 0; j < 4; j++) { o[j] = f2bf(xa[j]); o[4 + j] = f2bf(xb[j]); }
    *(u16x8*)(xbf + (size_t)t * HD + lane * 8) = o;

    float p[8];
#pragma unroll
    for (int e = 0; e < 8; e++) p[e] = 0.f;
#pragma unroll
    for (int j = 0; j < 4; j++) {
        int h0 = lane * 8 + j, h1 = lane * 8 + 4 + j;
        f4v wa0 = *(const f4v*)(Wg + h0 * 8);
        f4v wa1 = *(const f4v*)(Wg + h0 * 8 + 4);
        f4v wb0 = *(const f4v*)(Wg + h1 * 8);
        f4v wb1 = *(const f4v*)(Wg + h1 * 8 + 4);
#pragma unroll
        for (int e = 0; e < 4; e++) {
            p[e]     += xa[j] * wa0[e] + xb[j] * wb0[e];
            p[4 + e] += xa[j] * wa1[e] + xb[j] * wb1[e];
        }
    }
#pragma unroll
    for (int off = 32; off > 0; off >>= 1)
#pragma unroll
        for (int e = 0; e < 8; e++) p[e] += __shfl_xor(p[e], off, 64);
#pragma unroll
    for (int e = 0; e < 8; e++) p[e] += bg[e];
    float mx = p[0];
#pragma unroll
    for (int e = 1; e < 8; e++) mx = fmaxf(mx, p[e]);
    float pr[8]; float s = 0.f;
#pragma unroll
    for (int e = 0; e < 8; e++) { pr[e] = __expf(p[e] - mx); s += pr[e]; }
    float inv = 1.f / s;
#pragma unroll
    for (int e = 0; e < 8; e++) pr[e] *= inv;
    int i1 = 0; float v1 = pr[0];
#pragma unroll
    for (int e = 1; e < 8; e++) if (pr[e] > v1) { v1 = pr[e]; i1 = e; }
    int i2 = 0; float v2 = -1.f;
#pragma unroll
    for (int e = 0; e < 8; e++) if (e != i1 && pr[e] > v2) { v2 = pr[e]; i2 = e; }
    if (lane == 0) {
#pragma unroll
        for (int e = 0; e < 8; e++) comb[t * 8 + e] = (e == i1 || e == i2) ? pr[e] : 0.f;
        toke[t] = i1 | (i2 << 8);
        atomicAdd(ctrl + i1, 1);
        atomicAdd(ctrl + i2, 1);
    }
}

// ---------------- plan: padded segment offsets + tile map ----------------
__global__ void k_plan(int* __restrict__ ctrl) {
    if (threadIdx.x == 0 && blockIdx.x == 0) {
        int seg = 0, tt = 0;
        for (int e = 0; e < 8; e++) {
            ctrl[16 + e] = seg;
            int cnt = ctrl[e];
            int nt = (cnt + 63) >> 6;
            for (int i = 0; i < nt && tt < MAXTILES; i++) {
                ctrl[32 + tt * 3]     = e;
                ctrl[32 + tt * 3 + 1] = seg + i * 64;  // global row0
                ctrl[32 + tt * 3 + 2] = i * 64;        // in-segment row0
                tt++;
            }
            seg += nt * 64;
        }
        ctrl[24] = seg;
        ctrl[25] = tt;
    }
}

// ---------------- scatter: token -> gathered row lists ----------------
__global__ __launch_bounds__(256) void k_scatter(const int* __restrict__ toke, const float* __restrict__ comb,
                                                 int* __restrict__ ctrl, int* __restrict__ list,
                                                 float* __restrict__ roww) {
    int t = (blockIdx.x * 256 + threadIdx.x) & (NTOK - 1);
    int te = toke[t];
    int e1 = te & 7, e2 = (te >> 8) & 7;
    int p1 = atomicAdd(ctrl + 8 + e1, 1);
    int g1 = min(ctrl[16 + e1] + p1, MAXROWS - 1);
    list[g1] = t; roww[g1] = comb[t * 8 + e1];
    int p2 = atomicAdd(ctrl + 8 + e2, 1);
    int g2 = min(ctrl[16 + e2] + p2, MAXROWS - 1);
    list[g2] = t; roww[g2] = comb[t * 8 + e2];
}

// ---------------- fused expert FFN: 64-row tile, fused gelu(X@W1)@W2, f32 atomic out ----------------
__global__ __launch_bounds__(512) void k_main(const u16* __restrict__ xbf, const float* __restrict__ b1g,
                                              const float* __restrict__ b2g, const u16* __restrict__ W1T,
                                              const u16* __restrict__ W2T, const int* __restrict__ ctrl,
                                              const int* __restrict__ list, const float* __restrict__ roww,
                                              float* __restrict__ out) {
    int total = min(ctrl[25], MAXTILES);
    if ((int)blockIdx.x >= total) return;
    int e      = ctrl[32 + blockIdx.x * 3] & 7;
    int row0   = min(ctrl[32 + blockIdx.x * 3 + 1], MAXROWS - 64);
    int inseg0 = ctrl[32 + blockIdx.x * 3 + 2];
    int cnt = ctrl[e];
    int tid = threadIdx.x, wave = tid >> 6, lane = tid & 63;
    int quad = lane >> 4, l15 = lane & 15;
    // row stride 72 u16 = 144 B: b128 fragment reads 16B-aligned, 2-way bank aliased (free per m136)
    __shared__ alignas(16) u16 sH[2][64][72];

    int strip1 = wave >> 1;
    int fpair = (wave & 1) * 32;
    int mA = strip1 * 16 + l15;
    int tokA = (inseg0 + mA < cnt) ? (list[row0 + mA] & (NTOK - 1)) : 0;
    const u16* xrow = xbf + (size_t)tokA * HD + quad * 8;

    f4v Y[4][4];
#pragma unroll
    for (int s = 0; s < 4; s++)
#pragma unroll
        for (int ct = 0; ct < 4; ct++) Y[s][ct] = (f4v){0.f, 0.f, 0.f, 0.f};

    const u16* w1e = W1T + (size_t)e * FD * HD;   // [f][h]
    const u16* w2e = W2T + (size_t)e * HD * FD;   // [n][f]
    const float* b1e = b1g + e * FD;

    for (int c = 0; c < 32; c++) {
        int chF = c * 64, buf = c & 1;
        // ---- phase 1: Hc[64][64] = gelu(X[64,512] @ W1[:, chF:chF+64] + b1) ----
        f4v h0 = (f4v){0.f, 0.f, 0.f, 0.f}, h1 = (f4v){0.f, 0.f, 0.f, 0.f};
        const u16* bp0 = w1e + (size_t)(chF + fpair + l15) * HD + quad * 8;
        const u16* bp1 = bp0 + 16 * HD;
#pragma unroll
        for (int ks = 0; ks < 16; ks++) {
            s8v av  = *(const s8v*)(xrow + ks * 32);
            s8v b0  = *(const s8v*)(bp0 + ks * 32);
            s8v b1v = *(const s8v*)(bp1 + ks * 32);
            h0 = mfma16(av, b0, h0);
            h1 = mfma16(av, b1v, h1);
        }
        float bb0 = b1e[chF + fpair + l15];
        float bb1 = b1e[chF + fpair + 16 + l15];
        int mr = strip1 * 16 + quad * 4;
#pragma unroll
        for (int r = 0; r < 4; r++) {
            sH[buf][mr + r][fpair + l15]      = f2bf(gelu_f(h0[r] + bb0));
            sH[buf][mr + r][fpair + 16 + l15] = f2bf(gelu_f(h1[r] + bb1));
        }
        __syncthreads();
        // ---- phase 2: Y[64,512] += Hc[64,64] @ W2[chF:chF+64, :] ----
        int n0 = wave * 64;
#pragma unroll
        for (int ks = 0; ks < 2; ks++) {
            s8v aH[4];
#pragma unroll
            for (int s = 0; s < 4; s++)
                aH[s] = *(const s8v*)(&sH[buf][s * 16 + l15][ks * 32 + quad * 8]);
#pragma unroll
            for (int ct = 0; ct < 4; ct++) {
                int n = n0 + ct * 16 + l15;
                s8v bw = *(const s8v*)(w2e + (size_t)n * FD + chF + ks * 32 + quad * 8);
#pragma unroll
                for (int s = 0; s < 4; s++) Y[s][ct] = mfma16(aH[s], bw, Y[s][ct]);
            }
        }
    }
    // ---- epilogue: (Y + b2) * routing weight, atomic accumulate into f32 out ----
    float b2v[4];
#pragma unroll
    for (int ct = 0; ct < 4; ct++) b2v[ct] = b2g[e * HD + wave * 64 + ct * 16 + l15];
#pragma unroll
    for (int s = 0; s < 4; s++) {
#pragma unroll
        for (int r = 0; r < 4; r++) {
            int m = s * 16 + quad * 4 + r;
            bool val = (inseg0 + m) < cnt;
            int tok = list[row0 + m] & (NTOK - 1);   // pre-zeroed; pad rows read 0
            float wgt = val ? roww[row0 + m] : 0.f;
            float* orow = out + (size_t)tok * HD + wave * 64 + l15;
#pragma unroll
            for (int ct = 0; ct < 4; ct++)
                atomicAdd(orow + ct * 16, (Y[s][ct][r] + b2v[ct]) * wgt);
        }
    }
}

extern "C" void kernel_launch(void* const* d_in, const int* in_sizes, int n_in,
                              void* d_out, int out_size, void* d_ws, size_t ws_size,
                              hipStream_t stream) {
    const float* x  = (const float*)d_in[0];
    const float* Wg = (const float*)d_in[1];
    const float* bg = (const float*)d_in[2];
    const float* W1 = (const float*)d_in[3];
    const float* b1 = (const float*)d_in[4];
    const float* W2 = (const float*)d_in[5];
    const float* b2 = (const float*)d_in[6];
    (void)in_sizes; (void)n_in; (void)out_size;
    float* out = (float*)d_out;

    if (ws_size < WS_NEED) {
        // Diagnostic: not enough scratch — deterministic zero output (absmax 2.484 => ws too small)
        k_fallback<<<(NTOK * HD / 4) / 256, 256, 0, stream>>>(out);
        return;
    }

    char* ws = (char*)d_ws;
    int*   ctrl = (int*)(ws + CTRL_OFF);
    int*   toke = (int*)(ws + TOKE_OFF);
    float* comb = (float*)(ws + COMB_OFF);
    int*   list = (int*)(ws + LIST_OFF);
    float* roww = (float*)(ws + ROWW_OFF);
    u16*   xbf  = (u16*)(ws + XBF_OFF);
    u16*   w1t  = (u16*)(ws + W1T_OFF);
    u16*   w2t  = (u16*)(ws + W2T_OFF);

    k_zero<<<(NTOK * HD / 4) / 256, 256, 0, stream>>>(ctrl, list, roww, out);
    k_transpose<<<dim3(FD / 64, HD / 64, NE), dim3(256), 0, stream>>>(W1, w1t, HD, FD);
    k_transpose<<<dim3(HD / 64, FD / 64, NE), dim3(256), 0, stream>>>(W2, w2t, FD, HD);
    k_gate<<<NTOK / 4, 256, 0, stream>>>(x, Wg, bg, comb, toke, ctrl, xbf);
    k_plan<<<1, 64, 0, stream>>>(ctrl);
    k_scatter<<<NTOK / 256, 256, 0, stream>>>(toke, comb, ctrl, list, roww);
    k_main<<<MAXTILES, 512, 0, stream>>>(xbf, b1, b2, w1t, w2t, ctrl, list, roww, out);
}

// Round 6
// 1216.302 us; speedup vs baseline: 1.3861x; 1.3861x over previous
//
#include <hip/hip_runtime.h>
#include <stdint.h>

typedef unsigned short u16;
typedef unsigned int   u32;
typedef short  s8v  __attribute__((ext_vector_type(8)));
typedef __bf16 bf8v __attribute__((ext_vector_type(8)));
typedef float  f4v  __attribute__((ext_vector_type(4)));
typedef u16    u16x4 __attribute__((ext_vector_type(4)));
typedef u16    u16x8 __attribute__((ext_vector_type(8)));

#define NTOK   16384
#define HD     512
#define FD     2048
#define NE     8
#define MAXROWS 33280
#define MAXTILES 520
#define FCH    32
#define NCH    64   // FD / FCH

// ws layout (bytes); total need = 51380224 (ws_size >= 84.9 MB proven in R3/R4)
#define CTRL_OFF   0          // ints: [0..7] counts, [8..15] fill, [16..23] segoff, [24] rows, [25] tiles, [26] steal, [32..] map
#define TOKE_OFF   8192       // int[NTOK]
#define COMB_OFF   73728      // float[NTOK*8]
#define LIST_OFF   598016     // int[MAXROWS]
#define ROWW_OFF   731136     // float[MAXROWS]
#define XBF_OFF    1048576    // u16 [NTOK][HD]        bf16 copy of x
#define W1T_OFF    17825792   // u16 [NE][FD][HD]      bf16, transposed
#define W2T_OFF    34603008   // u16 [NE][HD][FD]      bf16, transposed
#define WS_NEED    51380224ull

__device__ __forceinline__ u16 f2bf(float f) {
    union { float f; u32 u; } v; v.f = f;
    u32 r = v.u + 0x7FFFu + ((v.u >> 16) & 1u);
    return (u16)(r >> 16);
}
__device__ __forceinline__ float gelu_f(float v) {
    float u = 0.7978845608028654f * (v + 0.044715f * v * v * v);
    float t = 1.f - 2.f / (__expf(2.f * u) + 1.f);
    return 0.5f * v * (1.f + t);
}

// mfma wrapper: ROCm versions differ on whether the builtin takes v8i16 or v8bf16.
template <typename V>
__device__ __forceinline__ auto mfma_try(V a, V b, f4v c, int)
    -> decltype(__builtin_amdgcn_mfma_f32_16x16x32_bf16(a, b, c, 0, 0, 0)) {
    return __builtin_amdgcn_mfma_f32_16x16x32_bf16(a, b, c, 0, 0, 0);
}
template <typename V>
__device__ __forceinline__ f4v mfma_try(V a, V b, f4v c, long) {
    return __builtin_amdgcn_mfma_f32_16x16x32_bf16(
        __builtin_bit_cast(bf8v, a), __builtin_bit_cast(bf8v, b), c, 0, 0, 0);
}
__device__ __forceinline__ f4v mfma16(s8v a, s8v b, f4v c) { return mfma_try(a, b, c, 0); }

// ---------------- diagnostic fallback ----------------
__global__ __launch_bounds__(256) void k_fallback(float* __restrict__ out) {
    int i = (blockIdx.x * 256 + threadIdx.x) * 4;
    *(f4v*)(out + i) = (f4v){0.f, 0.f, 0.f, 0.f};
}

// ---------------- zero per-call state ----------------
__global__ __launch_bounds__(256) void k_zero(int* __restrict__ ctrl, int* __restrict__ list,
                                              float* __restrict__ roww, float* __restrict__ out) {
    int id = blockIdx.x * 256 + threadIdx.x;
    *(f4v*)(out + (size_t)id * 4) = (f4v){0.f, 0.f, 0.f, 0.f};
    if (id < MAXROWS) { list[id] = 0; roww[id] = 0.f; }
    if (id < 64) ctrl[id] = 0;
}

// ---------------- transpose+cast (vectorized): f32 [R][C] -> bf16 [C][R] per expert ----------------
__global__ __launch_bounds__(256) void k_transpose(const float* __restrict__ in, u16* __restrict__ out,
                                                   int R, int C) {
    __shared__ float tile[64][65];
    size_t base = (size_t)blockIdx.z * R * C;
    const float* ip = in + base;
    u16* op = out + base;
    int c0 = blockIdx.x * 64, r0 = blockIdx.y * 64;
#pragma unroll
    for (int i = 0; i < 4; i++) {
        int idx = threadIdx.x + i * 256;
        int r = idx >> 4, c4 = (idx & 15) * 4;
        f4v v = *(const f4v*)(ip + (size_t)(r0 + r) * C + c0 + c4);
#pragma unroll
        for (int j = 0; j < 4; j++) tile[r][c4 + j] = v[j];
    }
    __syncthreads();
#pragma unroll
    for (int i = 0; i < 4; i++) {
        int idx = threadIdx.x + i * 256;
        int c = idx >> 4, r4 = (idx & 15) * 4;
        u16x4 o;
#pragma unroll
        for (int j = 0; j < 4; j++) o[j] = f2bf(tile[r4 + j][c]);
        *(u16x4*)(op + (size_t)(c0 + c) * R + r0 + r4) = o;
    }
}

// ---------------- gating (f32): softmax + top2, one wave/token; writes bf16 x copy; NO atomics ----------------
__global__ __launch_bounds__(256) void k_gate(const float* __restrict__ x, const float* __restrict__ Wg,
                                              const float* __restrict__ bg, float* __restrict__ comb,
                                              int* __restrict__ toke, u16* __restrict__ xbf) {
    int lane = threadIdx.x & 63;
    int t = (blockIdx.x * 4 + (threadIdx.x >> 6)) & (NTOK - 1);
    const float* xr = x + (size_t)t * HD;
    f4v xa = *(const f4v*)(xr + lane * 8);
    f4v xb = *(const f4v*)(xr + lane * 8 + 4);
    u16x8 o;
#pragma unroll
    for (int j = 0; j < 4; j++) { o[j] = f2bf(xa[j]); o[4 + j] = f2bf(xb[j]); }
    *(u16x8*)(xbf + (size_t)t * HD + lane * 8) = o;

    float p[8];
#pragma unroll
    for (int e = 0; e < 8; e++) p[e] = 0.f;
#pragma unroll
    for (int j = 0; j < 4; j++) {
        int h0 = lane * 8 + j, h1 = lane * 8 + 4 + j;
        f4v wa0 = *(const f4v*)(Wg + h0 * 8);
        f4v wa1 = *(const f4v*)(Wg + h0 * 8 + 4);
        f4v wb0 = *(const f4v*)(Wg + h1 * 8);
        f4v wb1 = *(const f4v*)(Wg + h1 * 8 + 4);
#pragma unroll
        for (int e = 0; e < 4; e++) {
            p[e]     += xa[j] * wa0[e] + xb[j] * wb0[e];
            p[4 + e] += xa[j] * wa1[e] + xb[j] * wb1[e];
        }
    }
#pragma unroll
    for (int off = 32; off > 0; off >>= 1)
#pragma unroll
        for (int e = 0; e < 8; e++) p[e] += __shfl_xor(p[e], off, 64);
#pragma unroll
    for (int e = 0; e < 8; e++) p[e] += bg[e];
    float mx = p[0];
#pragma unroll
    for (int e = 1; e < 8; e++) mx = fmaxf(mx, p[e]);
    float pr[8]; float s = 0.f;
#pragma unroll
    for (int e = 0; e < 8; e++) { pr[e] = __expf(p[e] - mx); s += pr[e]; }
    float inv = 1.f / s;
#pragma unroll
    for (int e = 0; e < 8; e++) pr[e] *= inv;
    int i1 = 0; float v1 = pr[0];
#pragma unroll
    for (int e = 1; e < 8; e++) if (pr[e] > v1) { v1 = pr[e]; i1 = e; }
    int i2 = 0; float v2 = -1.f;
#pragma unroll
    for (int e = 0; e < 8; e++) if (e != i1 && pr[e] > v2) { v2 = pr[e]; i2 = e; }
    if (lane == 0) {
#pragma unroll
        for (int e = 0; e < 8; e++) comb[t * 8 + e] = (e == i1 || e == i2) ? pr[e] : 0.f;
        toke[t] = i1 | (i2 << 8);
    }
}

// ---------------- counts via LDS aggregation (16 blocks x 8 = 128 global atomics total) ----------------
__global__ __launch_bounds__(1024) void k_count(const int* __restrict__ toke, int* __restrict__ ctrl) {
    __shared__ int sCnt[8];
    if (threadIdx.x < 8) sCnt[threadIdx.x] = 0;
    __syncthreads();
    int t = blockIdx.x * 1024 + threadIdx.x;
    int te = toke[t];
    atomicAdd(&sCnt[te & 7], 1);
    atomicAdd(&sCnt[(te >> 8) & 7], 1);
    __syncthreads();
    if (threadIdx.x < 8) atomicAdd(&ctrl[threadIdx.x], sCnt[threadIdx.x]);
}

// ---------------- plan: padded segment offsets + tile map (parallel fill) ----------------
__global__ __launch_bounds__(640) void k_plan(int* __restrict__ ctrl) {
    __shared__ int sOff[9], sSeg[9];
    if (threadIdx.x == 0) {
        int seg = 0, tt = 0;
        for (int e = 0; e < 8; e++) {
            sSeg[e] = seg; sOff[e] = tt;
            ctrl[16 + e] = seg;
            int nt = (ctrl[e] + 63) >> 6;
            tt += nt; seg += nt * 64;
        }
        sOff[8] = tt; sSeg[8] = seg;
        ctrl[24] = seg;
        ctrl[25] = (tt < MAXTILES) ? tt : MAXTILES;
    }
    __syncthreads();
    int ntile = sOff[8] < MAXTILES ? sOff[8] : MAXTILES;
    for (int tt = threadIdx.x; tt < ntile; tt += 640) {
        int e = 0;
        while (e < 7 && tt >= sOff[e + 1]) e++;
        int i = tt - sOff[e];
        ctrl[32 + tt * 3]     = e;
        ctrl[32 + tt * 3 + 1] = sSeg[e] + i * 64;
        ctrl[32 + tt * 3 + 2] = i * 64;
    }
}

// ---------------- scatter with LDS rank aggregation ----------------
__global__ __launch_bounds__(1024) void k_scatter(const int* __restrict__ toke, const float* __restrict__ comb,
                                                  int* __restrict__ ctrl, int* __restrict__ list,
                                                  float* __restrict__ roww) {
    __shared__ int sCnt[8], sBase[8];
    if (threadIdx.x < 8) sCnt[threadIdx.x] = 0;
    __syncthreads();
    int t = blockIdx.x * 1024 + threadIdx.x;
    int te = toke[t];
    int e1 = te & 7, e2 = (te >> 8) & 7;
    int r1 = atomicAdd(&sCnt[e1], 1);
    int r2 = atomicAdd(&sCnt[e2], 1);
    __syncthreads();
    if (threadIdx.x < 8) sBase[threadIdx.x] = atomicAdd(&ctrl[8 + threadIdx.x], sCnt[threadIdx.x]);
    __syncthreads();
    int g1 = min(ctrl[16 + e1] + sBase[e1] + r1, MAXROWS - 1);
    list[g1] = t; roww[g1] = comb[t * 8 + e1];
    int g2 = min(ctrl[16 + e2] + sBase[e2] + r2, MAXROWS - 1);
    list[g2] = t; roww[g2] = comb[t * 8 + e2];
}

// ---------------- fused expert FFN v2: persistent work-steal, LDS-staged weights ----------------
// Per tile (64 rows, expert e), loop 64 F-chunks of 32:
//   stage sW1[32][512] (XOR-swizzled) + sW2[512][40] (padded) -> phase1 MFMA (H chunk)
//   -> gelu -> sH[64][40] -> phase2 MFMA accumulate Y[64][512].
__global__ __launch_bounds__(512, 4) void k_main(const u16* __restrict__ xbf, const float* __restrict__ b1g,
                                                 const float* __restrict__ b2g, const u16* __restrict__ W1T,
                                                 const u16* __restrict__ W2T, const int* __restrict__ ctrl,
                                                 int* __restrict__ steal, const int* __restrict__ list,
                                                 const float* __restrict__ roww, float* __restrict__ out) {
    __shared__ u16 sW1[32 * 512];   // XOR-swizzled chunks: phys = (c&~7)|((c&7)^(f&7))
    __shared__ u16 sW2[512 * 40];   // row stride 40 els = 80 B (16B-aligned, 2-way banks)
    __shared__ u16 sH[64 * 40];
    __shared__ int sTile;
    const int tid = threadIdx.x, wave = tid >> 6, lane = tid & 63;
    const int quad = lane >> 4, l15 = lane & 15;
    const int m4 = wave & 3, f2 = wave >> 2;       // phase-1 fragment assignment
    const int fs = f2 * 16 + l15;                  // f-row within chunk [0,32)
    const int total = min(ctrl[25], MAXTILES);

    for (;;) {
        if (tid == 0) sTile = atomicAdd(steal, 1);
        __syncthreads();
        int bt = sTile;
        if (bt >= total) break;
        int e      = ctrl[32 + bt * 3] & 7;
        int row0   = min(ctrl[32 + bt * 3 + 1], MAXROWS - 64);
        int inseg0 = ctrl[32 + bt * 3 + 2];
        int cnt    = ctrl[e];
        const u16* w1e = W1T + (size_t)e * FD * HD;   // [f][h]
        const u16* w2e = W2T + (size_t)e * HD * FD;   // [n][f]
        const float* b1e = b1g + e * FD;

        int mA = m4 * 16 + l15;
        int tokA = (inseg0 + mA < cnt) ? (list[row0 + mA] & (NTOK - 1)) : 0;
        const u16* xrow = xbf + (size_t)tokA * HD + quad * 8;

        f4v Y[4][4];
#pragma unroll
        for (int mb = 0; mb < 4; mb++)
#pragma unroll
            for (int nb = 0; nb < 4; nb++) Y[mb][nb] = (f4v){0.f, 0.f, 0.f, 0.f};

        for (int c = 0; c < NCH; c++) {
            __syncthreads();   // all waves done with prev chunk's sW1/sW2/sH reads
            // ---- stage: sW1 (32x512, swizzled) + sW2 (512x40 padded) ----
#pragma unroll
            for (int t8 = 0; t8 < 4; t8++) {
                int u = t8 * 512 + tid;
                int f = u >> 6, cu = u & 63;
                int phys = (cu & ~7) | ((cu & 7) ^ (f & 7));
                u16x8 v = *(const u16x8*)(w1e + (size_t)(c * FCH + f) * HD + cu * 8);
                *(u16x8*)(sW1 + f * 512 + phys * 8) = v;
            }
#pragma unroll
            for (int t8 = 0; t8 < 4; t8++) {
                int u = t8 * 512 + tid;
                int n = u >> 2, cu = u & 3;
                u16x8 v = *(const u16x8*)(w2e + (size_t)n * FD + c * FCH + cu * 8);
                *(u16x8*)(sW2 + n * 40 + cu * 8) = v;
            }
            __syncthreads();   // staging visible
            // ---- phase 1: H[:,c] frag per wave (m4, f2), K=512 ----
            f4v h = (f4v){0.f, 0.f, 0.f, 0.f};
#pragma unroll
            for (int ks = 0; ks < 16; ks++) {
                s8v a = *(const s8v*)(xrow + ks * 32);
                int cidx = ks * 4 + quad;
                int phys = (cidx & ~7) | ((cidx & 7) ^ (fs & 7));
                s8v b = *(const s8v*)(sW1 + fs * 512 + phys * 8);
                h = mfma16(a, b, h);
            }
            float bb = b1e[c * FCH + fs];
#pragma unroll
            for (int r = 0; r < 4; r++)
                sH[(m4 * 16 + quad * 4 + r) * 40 + fs] = f2bf(gelu_f(h[r] + bb));
            __syncthreads();   // sH visible
            // ---- phase 2: Y += H_chunk @ W2_chunk, wave covers n in [wave*64, wave*64+64) ----
            s8v aH[4];
#pragma unroll
            for (int mb = 0; mb < 4; mb++)
                aH[mb] = *(const s8v*)(sH + (mb * 16 + l15) * 40 + quad * 8);
#pragma unroll
            for (int nb = 0; nb < 4; nb++) {
                int n = wave * 64 + nb * 16 + l15;
                s8v bw = *(const s8v*)(sW2 + n * 40 + quad * 8);
#pragma unroll
                for (int mb = 0; mb < 4; mb++) Y[mb][nb] = mfma16(aH[mb], bw, Y[mb][nb]);
            }
        }
        // ---- epilogue: (Y + b2) * routing weight, atomic accumulate into f32 out ----
        float b2v[4];
#pragma unroll
        for (int nb = 0; nb < 4; nb++) b2v[nb] = b2g[e * HD + wave * 64 + nb * 16 + l15];
#pragma unroll
        for (int mb = 0; mb < 4; mb++) {
#pragma unroll
            for (int r = 0; r < 4; r++) {
                int m = mb * 16 + quad * 4 + r;
                bool val = (inseg0 + m) < cnt;
                int tok = list[row0 + m] & (NTOK - 1);
                float wgt = val ? roww[row0 + m] : 0.f;
                float* orow = out + (size_t)tok * HD + wave * 64 + l15;
#pragma unroll
                for (int nb = 0; nb < 4; nb++)
                    atomicAdd(orow + nb * 16, (Y[mb][nb][r] + b2v[nb]) * wgt);
            }
        }
    }
}

extern "C" void kernel_launch(void* const* d_in, const int* in_sizes, int n_in,
                              void* d_out, int out_size, void* d_ws, size_t ws_size,
                              hipStream_t stream) {
    const float* x  = (const float*)d_in[0];
    const float* Wg = (const float*)d_in[1];
    const float* bg = (const float*)d_in[2];
    const float* W1 = (const float*)d_in[3];
    const float* b1 = (const float*)d_in[4];
    const float* W2 = (const float*)d_in[5];
    const float* b2 = (const float*)d_in[6];
    (void)in_sizes; (void)n_in; (void)out_size;
    float* out = (float*)d_out;

    if (ws_size < WS_NEED) {
        k_fallback<<<(NTOK * HD / 4) / 256, 256, 0, stream>>>(out);
        return;
    }

    char* ws = (char*)d_ws;
    int*   ctrl = (int*)(ws + CTRL_OFF);
    int*   toke = (int*)(ws + TOKE_OFF);
    float* comb = (float*)(ws + COMB_OFF);
    int*   list = (int*)(ws + LIST_OFF);
    float* roww = (float*)(ws + ROWW_OFF);
    u16*   xbf  = (u16*)(ws + XBF_OFF);
    u16*   w1t  = (u16*)(ws + W1T_OFF);
    u16*   w2t  = (u16*)(ws + W2T_OFF);

    k_zero<<<(NTOK * HD / 4) / 256, 256, 0, stream>>>(ctrl, list, roww, out);
    k_transpose<<<dim3(FD / 64, HD / 64, NE), dim3(256), 0, stream>>>(W1, w1t, HD, FD);
    k_transpose<<<dim3(HD / 64, FD / 64, NE), dim3(256), 0, stream>>>(W2, w2t, FD, HD);
    k_gate<<<NTOK / 4, 256, 0, stream>>>(x, Wg, bg, comb, toke, xbf);
    k_count<<<NTOK / 1024, 1024, 0, stream>>>(toke, ctrl);
    k_plan<<<1, 640, 0, stream>>>(ctrl);
    k_scatter<<<NTOK / 1024, 1024, 0, stream>>>(toke, comb, ctrl, list, roww);
    k_main<<<512, 512, 0, stream>>>(xbf, b1, b2, w1t, w2t, ctrl, ctrl + 26, list, roww, out);
}